// Round 7
// baseline (4936.811 us; speedup 1.0000x reference)
//
#include <hip/hip_runtime.h>

#define BB 512
#define V0 1024
#define V1 256
#define E0 8192
#define E1 2048

// ---------------- CSR build (deterministic) ----------------
__global__ void k_deg(const int* __restrict__ rows, int E, int* __restrict__ deg) {
    int t = blockIdx.x * 256 + threadIdx.x;
    if (t < E) atomicAdd(&deg[rows[t]], 1);
}

__global__ void k_scan(const int* __restrict__ deg, int* __restrict__ off, int V) {
    __shared__ int s[1024];
    int t = threadIdx.x;
    s[t] = (t < V) ? deg[t] : 0;
    __syncthreads();
    for (int d = 1; d < 1024; d <<= 1) {
        int val = (t >= d) ? s[t - d] : 0;
        __syncthreads();
        s[t] += val;
        __syncthreads();
    }
    if (t < V) off[t + 1] = s[t];
    if (t == 0) off[0] = 0;
}

// stable fill: edge e goes to off[row] + (#earlier edges with same row); packed (col,val)
__global__ void k_fillp(const int* __restrict__ rows, const int* __restrict__ cols,
                        const float* __restrict__ vals, int E,
                        const int* __restrict__ off, int2* __restrict__ epk) {
    __shared__ int rs[256];
    int e = blockIdx.x * 256 + threadIdx.x;
    int r = (e < E) ? rows[e] : -1;
    int rank = 0;
    for (int c0 = 0; c0 <= (int)blockIdx.x; ++c0) {
        __syncthreads();
        int idx = c0 * 256 + threadIdx.x;
        rs[threadIdx.x] = (idx < E) ? rows[idx] : -2;
        __syncthreads();
        int lim = e - c0 * 256;
        if (lim > 256) lim = 256;
        for (int j = 0; j < lim; ++j) rank += (rs[j] == r) ? 1 : 0;
    }
    if (e < E) {
        int p = off[r] + rank;
        epk[p] = make_int2(cols[e], __float_as_int(vals[e]));
    }
}

// ---------------- fused cheby conv: full-width slab, b128 gathers ----------------
// xin [B, V, FIN], out [B, V or V/4, FOUT]. Block = 1 batch, V*OS threads.
// One slab xs[V][FHP] (vertex-major, XOR-swizzled 16B units), reused x0 -> x1.
// Per phase: stage x0 (keep in regs) | sync | GEMM t0; gather1 (b128) | sync |
//            publish x1; GEMM t1 | sync | gather2; GEMM t2 | (sync)
// Wl = transformed panels (W0-W2 | W1 | 2*W2), read as wave-uniform b128 broadcasts.
// OS: output split (thread owns FOUT/OS outputs; x-work duplicated across os).
// POOL: 0 none, 1 quad-lane max over 4 consecutive vertices.
template <int V, int FIN, int FH, int FOUT, int OS, int POOL>
__global__ __launch_bounds__(V * OS) void k_conv(
    const float* __restrict__ xin, const float* __restrict__ W,
    const float* __restrict__ bias, float* __restrict__ out,
    const int* __restrict__ off, const int2* __restrict__ epk) {
    constexpr int NPH = FIN / FH;
    constexpr bool SC3 = (FH == 3);
    constexpr int FHP = SC3 ? 4 : FH;
    constexpr int Q = FHP / 4;          // 16B units per column
    constexpr int OW = FOUT / OS;       // outputs per thread
    constexpr int NT = V * OS;
    __shared__ float xs[V * FHP];
    __shared__ float Wl[3 * FH * FOUT];
    float4* xs4 = (float4*)xs;

    const int t = threadIdx.x;
    const int vloc = (OS == 1) ? t : (t % V);
    const int os = (OS == 1) ? 0 : (t / V);
    const int b = blockIdx.x;
    const int o0 = os * OW;
    const int s0 = off[vloc], e0 = off[vloc + 1];

    float acc[OW];
#pragma unroll
    for (int o = 0; o < OW; ++o) acc[o] = 0.f;

    float xr[FHP], xg[FHP];

#define GEMM_TERM(TERM, XR)                                                   \
    {                                                                         \
        _Pragma("unroll") for (int f_ = 0; f_ < FH; ++f_) {                   \
            const float uv_ = (XR)[f_];                                       \
            _Pragma("unroll") for (int j_ = 0; j_ < OW / 4; ++j_) {           \
                float4 wv_ = *(const float4*)&Wl[((TERM)*FH + f_) * FOUT + o0 + 4 * j_]; \
                acc[4 * j_ + 0] += uv_ * wv_.x;                               \
                acc[4 * j_ + 1] += uv_ * wv_.y;                               \
                acc[4 * j_ + 2] += uv_ * wv_.z;                               \
                acc[4 * j_ + 3] += uv_ * wv_.w;                               \
            }                                                                 \
        }                                                                     \
    }

#define GATHER_PASS(XG)                                                       \
    {                                                                         \
        _Pragma("unroll") for (int f_ = 0; f_ < FHP; ++f_) (XG)[f_] = 0.f;    \
        for (int p_ = s0; p_ < e0; ++p_) {                                    \
            int2 e_ = epk[p_];                                                \
            int c_ = e_.x;                                                    \
            float w_ = __int_as_float(e_.y);                                  \
            _Pragma("unroll") for (int g_ = 0; g_ < Q; ++g_) {                \
                float4 q_ = xs4[c_ * Q + (g_ ^ (c_ & (Q - 1)))];              \
                (XG)[4 * g_ + 0] += w_ * q_.x;                                \
                (XG)[4 * g_ + 1] += w_ * q_.y;                                \
                (XG)[4 * g_ + 2] += w_ * q_.z;                                \
                (XG)[4 * g_ + 3] += w_ * q_.w;                                \
            }                                                                 \
        }                                                                     \
    }

    for (int ph = 0; ph < NPH; ++ph) {
        // ---- transformed weight panels for this slice
        for (int idx = t; idx < FH * FOUT; idx += NT) {
            int f = idx / FOUT, o = idx - f * FOUT;
            int fg = ph * FH + f;
            float w0 = W[o * (3 * FIN) + fg * 3 + 0];
            float w1 = W[o * (3 * FIN) + fg * 3 + 1];
            float w2 = W[o * (3 * FIN) + fg * 3 + 2];
            Wl[(0 * FH + f) * FOUT + o] = w0 - w2;
            Wl[(1 * FH + f) * FOUT + o] = w1;
            Wl[(2 * FH + f) * FOUT + o] = 2.f * w2;
        }
        // ---- stage x0 (keep own column in regs)
        if constexpr (SC3) {
            xr[0] = xin[((size_t)b * V + vloc) * 3 + 0];
            xr[1] = xin[((size_t)b * V + vloc) * 3 + 1];
            xr[2] = xin[((size_t)b * V + vloc) * 3 + 2];
            xr[3] = 0.f;
            if (os == 0) {
                float4 q = {xr[0], xr[1], xr[2], 0.f};
                xs4[vloc] = q;
            }
        } else {
#pragma unroll
            for (int g = 0; g < Q; ++g) {
                float4 q = *(const float4*)(xin + ((size_t)b * V + vloc) * FIN + ph * FH + 4 * g);
                xr[4 * g + 0] = q.x; xr[4 * g + 1] = q.y;
                xr[4 * g + 2] = q.z; xr[4 * g + 3] = q.w;
                if (os == 0) xs4[vloc * Q + (g ^ (vloc & (Q - 1)))] = q;
            }
        }
        __syncthreads();
        // ---- term0 (x0) + gather1
        GEMM_TERM(0, xr)
        GATHER_PASS(xg)
        __syncthreads();
        // ---- publish x1, term1 (x1)
        if (os == 0) {
#pragma unroll
            for (int g = 0; g < Q; ++g) {
                float4 q = {xg[4 * g + 0], xg[4 * g + 1], xg[4 * g + 2], xg[4 * g + 3]};
                xs4[vloc * Q + (g ^ (vloc & (Q - 1)))] = q;
            }
        }
        GEMM_TERM(1, xg)
        __syncthreads();
        // ---- gather2, term2 (x2raw)
        GATHER_PASS(xr)
        GEMM_TERM(2, xr)
        if (ph != NPH - 1) __syncthreads();
    }
#undef GEMM_TERM
#undef GATHER_PASS

    // ---- epilogue
    if constexpr (POOL == 0) {
        float* orow = out + ((size_t)b * V + vloc) * FOUT + o0;
#pragma unroll
        for (int j = 0; j < OW / 4; ++j) {
            float4 st;
            st.x = acc[4 * j + 0] + bias[o0 + 4 * j + 0];
            st.y = acc[4 * j + 1] + bias[o0 + 4 * j + 1];
            st.z = acc[4 * j + 2] + bias[o0 + 4 * j + 2];
            st.w = acc[4 * j + 3] + bias[o0 + 4 * j + 3];
            ((float4*)orow)[j] = st;
        }
    } else {
#pragma unroll
        for (int o = 0; o < OW; ++o) {
            float m = acc[o];
            m = fmaxf(m, __shfl_xor(m, 1));
            m = fmaxf(m, __shfl_xor(m, 2));
            acc[o] = m + bias[o0 + o];
        }
        const int r = vloc & 3;
        const int vt = vloc >> 2;
        float* orow = out + ((size_t)b * (V / 4) + vt) * FOUT + o0 + r * (OW / 4);
#pragma unroll
        for (int rq = 0; rq < 4; ++rq) {
            if (r == rq) {
#pragma unroll
                for (int jj = 0; jj < OW / 16; ++jj) {
                    float4 st = {acc[rq * (OW / 4) + 4 * jj + 0],
                                 acc[rq * (OW / 4) + 4 * jj + 1],
                                 acc[rq * (OW / 4) + 4 * jj + 2],
                                 acc[rq * (OW / 4) + 4 * jj + 3]};
                    ((float4*)orow)[jj] = st;
                }
            }
        }
    }
}

// ---------------- FC1: C[512,512] = A[512,4096] * W[512,4096]^T, split-K=16 ----------------
__global__ __launch_bounds__(256) void k_fc1(const float* __restrict__ A,
                                             const float* __restrict__ W,
                                             float* __restrict__ part) {
    __shared__ float As[16][128];
    __shared__ float Bs[16][128];
    const int tid = threadIdx.x;
    const int bm = blockIdx.x, bn = blockIdx.y, bz = blockIdx.z;
    const int m0 = (tid >> 4) << 3;
    const int n0 = (tid & 15) << 3;
    float acc[8][8];
#pragma unroll
    for (int i = 0; i < 8; ++i)
#pragma unroll
        for (int j = 0; j < 8; ++j) acc[i][j] = 0.f;
    const int r = tid >> 1;
    const int c8 = (tid & 1) << 3;
    const float* Ar = A + (size_t)(bm * 128 + r) * 4096 + bz * 256 + c8;
    const float* Wr = W + (size_t)(bn * 128 + r) * 4096 + bz * 256 + c8;
    for (int kt = 0; kt < 256; kt += 16) {
        float4 a0 = *(const float4*)(Ar + kt);
        float4 a1 = *(const float4*)(Ar + kt + 4);
        float4 w0 = *(const float4*)(Wr + kt);
        float4 w1 = *(const float4*)(Wr + kt + 4);
        __syncthreads();
        As[c8 + 0][r] = a0.x; As[c8 + 1][r] = a0.y; As[c8 + 2][r] = a0.z; As[c8 + 3][r] = a0.w;
        As[c8 + 4][r] = a1.x; As[c8 + 5][r] = a1.y; As[c8 + 6][r] = a1.z; As[c8 + 7][r] = a1.w;
        Bs[c8 + 0][r] = w0.x; Bs[c8 + 1][r] = w0.y; Bs[c8 + 2][r] = w0.z; Bs[c8 + 3][r] = w0.w;
        Bs[c8 + 4][r] = w1.x; Bs[c8 + 5][r] = w1.y; Bs[c8 + 6][r] = w1.z; Bs[c8 + 7][r] = w1.w;
        __syncthreads();
#pragma unroll
        for (int k = 0; k < 16; ++k) {
            float am[8], bn_[8];
            *(float4*)&am[0] = *(const float4*)&As[k][m0];
            *(float4*)&am[4] = *(const float4*)&As[k][m0 + 4];
            *(float4*)&bn_[0] = *(const float4*)&Bs[k][n0];
            *(float4*)&bn_[4] = *(const float4*)&Bs[k][n0 + 4];
#pragma unroll
            for (int i = 0; i < 8; ++i)
#pragma unroll
                for (int j = 0; j < 8; ++j) acc[i][j] += am[i] * bn_[j];
        }
    }
    float* P = part + ((size_t)bz * 512 + bm * 128 + m0) * 512 + bn * 128 + n0;
#pragma unroll
    for (int i = 0; i < 8; ++i) {
        float4 s0 = {acc[i][0], acc[i][1], acc[i][2], acc[i][3]};
        float4 s1 = {acc[i][4], acc[i][5], acc[i][6], acc[i][7]};
        *(float4*)(P + i * 512) = s0;
        *(float4*)(P + i * 512 + 4) = s1;
    }
}

__global__ void k_fc1red(const float* __restrict__ part, const float* __restrict__ bias,
                         float* __restrict__ out) {
    int t = blockIdx.x * 256 + threadIdx.x;  // 512*512
    float s = bias[t & 511];
#pragma unroll
    for (int z = 0; z < 16; ++z) s += part[(size_t)z * 262144 + t];
    out[t] = s;
}

// ---------------- FC2: out[512,63] ----------------
__global__ void k_fc2(const float* __restrict__ X, const float* __restrict__ W,
                      const float* __restrict__ bias, float* __restrict__ out) {
    int b = blockIdx.x, c = threadIdx.x;
    if (c >= 63) return;
    const float4* xr = (const float4*)(X + b * 512);
    const float4* wr = (const float4*)(W + c * 512);
    float s = 0.f;
    for (int k = 0; k < 128; ++k) {
        float4 xv = xr[k], wv = wr[k];
        s += xv.x * wv.x + xv.y * wv.y + xv.z * wv.z + xv.w * wv.w;
    }
    out[b * 63 + c] = s + bias[c];
}

extern "C" void kernel_launch(void* const* d_in, const int* in_sizes, int n_in,
                              void* d_out, int out_size, void* d_ws, size_t ws_size,
                              hipStream_t stream) {
    const float* x = (const float*)d_in[0];
    const int* rows0 = (const int*)d_in[1];
    const int* cols0 = (const int*)d_in[2];
    const float* vals0 = (const float*)d_in[3];
    const int* rows1 = (const int*)d_in[4];
    const int* cols1 = (const int*)d_in[5];
    const float* vals1 = (const float*)d_in[6];
    const float* W0 = (const float*)d_in[7];  const float* b0 = (const float*)d_in[8];
    const float* W1 = (const float*)d_in[9];  const float* b1 = (const float*)d_in[10];
    const float* W2 = (const float*)d_in[11]; const float* b2 = (const float*)d_in[12];
    const float* W3 = (const float*)d_in[13]; const float* b3 = (const float*)d_in[14];
    const float* fcW1 = (const float*)d_in[15]; const float* fcb1 = (const float*)d_in[16];
    const float* fcW2 = (const float*)d_in[17]; const float* fcb2 = (const float*)d_in[18];
    float* out = (float*)d_out;

    float* wsf = (float*)d_ws;
    // small region
    int* off0 = (int*)(wsf + 0);          // 1025
    int* off1 = (int*)(wsf + 1088);       // 257
    int* deg0 = (int*)(wsf + 1408);       // 1024
    int* deg1 = (int*)(wsf + 2432);       // 256
    int2* epk0 = (int2*)(wsf + 4096);     // 8192 int2 -> [4096, 20480)
    int2* epk1 = (int2*)(wsf + 20480);    // 2048 int2 -> [20480, 24576)

    float* A1  = wsf + 65536;             // 16,777,216  [B,1024,32]
    float* P1  = A1 + 16777216;           //  4,194,304  [B,256,32]
    float* A3  = P1 + 4194304;            //  8,388,608  [B,256,64]
    float* FCB = A3 + 8388608;            //  2,097,152  [B,4096]
    float* PART = FCB + 2097152;          //  4,194,304  [16,512,512]
    float* FC1O = PART + 4194304;         //    262,144  [512,512]
    (void)in_sizes; (void)n_in; (void)out_size; (void)ws_size;

    hipMemsetAsync(wsf, 0, 4096 * 4, stream);
    k_deg<<<E0 / 256, 256, 0, stream>>>(rows0, E0, deg0);
    k_deg<<<E1 / 256, 256, 0, stream>>>(rows1, E1, deg1);
    k_scan<<<1, 1024, 0, stream>>>(deg0, off0, V0);
    k_scan<<<1, 1024, 0, stream>>>(deg1, off1, V1);
    k_fillp<<<E0 / 256, 256, 0, stream>>>(rows0, cols0, vals0, E0, off0, epk0);
    k_fillp<<<E1 / 256, 256, 0, stream>>>(rows1, cols1, vals1, E1, off1, epk1);

    // conv1: 3->32, 1024 thr, LDS ~17.6 KB, 2 blk/CU
    k_conv<V0, 3, 3, 32, 1, 0><<<BB, 1024, 0, stream>>>(x, W0, b0, A1, off0, epk0);
    // conv2+pool: 32->32, full-width FH=32, 1024 thr, LDS 140 KB
    k_conv<V0, 32, 32, 32, 1, 1><<<BB, 1024, 0, stream>>>(A1, W1, b1, P1, off0, epk0);
    // conv3: 32->64, OS=2, 512 thr, LDS 56 KB, 2 blk/CU
    k_conv<V1, 32, 32, 64, 2, 0><<<BB, 512, 0, stream>>>(P1, W2, b2, A3, off1, epk1);
    // conv4+pool: 64->64, OS=2, FH=32 (2 phases), 512 thr, LDS 56 KB, 2 blk/CU
    k_conv<V1, 64, 32, 64, 2, 1><<<BB, 512, 0, stream>>>(A3, W3, b3, FCB, off1, epk1);

    // head (FCB is [B, 4096] in reference order)
    k_fc1<<<dim3(4, 4, 16), 256, 0, stream>>>(FCB, fcW1, PART);
    k_fc1red<<<1024, 256, 0, stream>>>(PART, fcb1, FC1O);
    k_fc2<<<BB, 64, 0, stream>>>(FC1O, fcW2, fcb2, out);
}

// Round 8
// 1387.538 us; speedup vs baseline: 3.5580x; 3.5580x over previous
//
#include <hip/hip_runtime.h>

#define BB 512
#define V0 1024
#define V1 256
#define E0 8192
#define E1 2048

// ---------------- CSR build (deterministic) ----------------
__global__ void k_deg(const int* __restrict__ rows, int E, int* __restrict__ deg) {
    int t = blockIdx.x * 256 + threadIdx.x;
    if (t < E) atomicAdd(&deg[rows[t]], 1);
}

__global__ void k_scan(const int* __restrict__ deg, int* __restrict__ off, int V) {
    __shared__ int s[1024];
    int t = threadIdx.x;
    s[t] = (t < V) ? deg[t] : 0;
    __syncthreads();
    for (int d = 1; d < 1024; d <<= 1) {
        int val = (t >= d) ? s[t - d] : 0;
        __syncthreads();
        s[t] += val;
        __syncthreads();
    }
    if (t < V) off[t + 1] = s[t];
    if (t == 0) off[0] = 0;
}

// stable fill: edge e goes to off[row] + (#earlier edges with same row); packed (col,val)
__global__ void k_fillp(const int* __restrict__ rows, const int* __restrict__ cols,
                        const float* __restrict__ vals, int E,
                        const int* __restrict__ off, int2* __restrict__ epk) {
    __shared__ int rs[256];
    int e = blockIdx.x * 256 + threadIdx.x;
    int r = (e < E) ? rows[e] : -1;
    int rank = 0;
    for (int c0 = 0; c0 <= (int)blockIdx.x; ++c0) {
        __syncthreads();
        int idx = c0 * 256 + threadIdx.x;
        rs[threadIdx.x] = (idx < E) ? rows[idx] : -2;
        __syncthreads();
        int lim = e - c0 * 256;
        if (lim > 256) lim = 256;
        for (int j = 0; j < lim; ++j) rank += (rs[j] == r) ? 1 : 0;
    }
    if (e < E) {
        int p = off[r] + rank;
        epk[p] = make_int2(cols[e], __float_as_int(vals[e]));
    }
}

// ---------------- fused cheby conv: pair-major single slab, b64 gathers ----------------
// xin [B, V, FIN], out [B, V or V/4, FOUT]. Block = 1 batch x (V*OS) threads.
// LDS: ONE slab xs[NP2][NCP][2] (feature-pair-major, padded cols) reused x0->x1->x2;
//      Wl[3][FHP][FOUT] transformed weight panels (W0-W2 | W1 | 2*W2), pad rows zero.
// Phase: Wl+stage | s | gather1+term0 | s | publish x1 | s | gather2+term1 | s |
//        publish x2 | s | term2 | s
// GEMM microtile: thread = (vt, ot): 4 vertices x OW outputs, acc[4][OW]; A from slab
// as b128 (2 k-steps x 2 vertices per read), Wl b128 broadcasts.
// OS=2 splits outputs AND gather feature-pairs across halves.
// POOL: 0 none, 1 register max over the thread's 4 vertices (stride-4 pool).
template <int V, int FIN, int FH, int FOUT, int OS, int POOL>
__global__ __launch_bounds__(V * OS) void k_conv(
    const float* __restrict__ xin, const float* __restrict__ W,
    const float* __restrict__ bias, float* __restrict__ out,
    const int* __restrict__ off, const int2* __restrict__ epk) {
    constexpr int FHP = (FH == 3) ? 4 : FH;
    constexpr int NPH = FIN / FH;
    constexpr int NP2 = FHP / 2;       // feature pairs
    constexpr int Q = FHP / 4;         // float4 groups
    constexpr int GCNT = (Q / OS < 1) ? 1 : (Q / OS);  // float4 groups per thread
    constexpr int NT = V * OS;
    constexpr int NCP = V + 4;         // padded column stride
    constexpr int OWS = FOUT / OS;
    constexpr int OW = OWS / 4;
    __shared__ float xs[NP2 * NCP * 2];
    __shared__ float Wl[3 * FHP * FOUT];

    const int t = threadIdx.x;
    const int os = (OS == 1) ? 0 : (t / V);
    const int vloc = (OS == 1) ? t : (t - os * V);
    const int b = blockIdx.x;
    const int vt = vloc >> 2;
    const int ot = vloc & 3;
    const int o0 = os * OWS + ot * OW;
    const int s0 = off[vloc], e0 = off[vloc + 1];

    float acc[4][OW];
#pragma unroll
    for (int i = 0; i < 4; ++i)
#pragma unroll
        for (int o = 0; o < OW; ++o) acc[i][o] = 0.f;

    float xr[4 * GCNT], xg[4 * GCNT];

#define STAGE_WRITE(XR)                                                        \
    {                                                                          \
        _Pragma("unroll") for (int gg_ = 0; gg_ < GCNT; ++gg_) {               \
            int g_ = os * GCNT + gg_;                                          \
            float2 qa_ = {(XR)[4 * gg_ + 0], (XR)[4 * gg_ + 1]};               \
            float2 qb_ = {(XR)[4 * gg_ + 2], (XR)[4 * gg_ + 3]};               \
            *(float2*)&xs[((2 * g_) * NCP + vloc) * 2] = qa_;                  \
            *(float2*)&xs[((2 * g_ + 1) * NCP + vloc) * 2] = qb_;              \
        }                                                                      \
    }

#define GATHER(XR)                                                             \
    {                                                                          \
        _Pragma("unroll") for (int f_ = 0; f_ < 4 * GCNT; ++f_) (XR)[f_] = 0.f;\
        for (int p_ = s0; p_ < e0; ++p_) {                                     \
            int2 e_ = epk[p_];                                                 \
            int c_ = e_.x;                                                     \
            float w_ = __int_as_float(e_.y);                                   \
            _Pragma("unroll") for (int gg_ = 0; gg_ < GCNT; ++gg_) {           \
                int g_ = os * GCNT + gg_;                                      \
                float2 qa_ = *(const float2*)&xs[((2 * g_) * NCP + c_) * 2];   \
                float2 qb_ = *(const float2*)&xs[((2 * g_ + 1) * NCP + c_) * 2];\
                (XR)[4 * gg_ + 0] += w_ * qa_.x;                               \
                (XR)[4 * gg_ + 1] += w_ * qa_.y;                               \
                (XR)[4 * gg_ + 2] += w_ * qb_.x;                               \
                (XR)[4 * gg_ + 3] += w_ * qb_.y;                               \
            }                                                                  \
        }                                                                      \
    }

#define TERM(TRM)                                                              \
    {                                                                          \
        _Pragma("unroll") for (int p_ = 0; p_ < NP2; ++p_) {                   \
            float4 aA_ = *(const float4*)&xs[(p_ * NCP + 4 * vt) * 2];         \
            float4 aB_ = *(const float4*)&xs[(p_ * NCP + 4 * vt) * 2 + 4];     \
            float k0v_[4] = {aA_.x, aA_.z, aB_.x, aB_.z};                      \
            float k1v_[4] = {aA_.y, aA_.w, aB_.y, aB_.w};                      \
            _Pragma("unroll") for (int j_ = 0; j_ < OW / 4; ++j_) {            \
                float4 w0v_ = *(const float4*)&Wl[((TRM) * FHP + 2 * p_) * FOUT + o0 + 4 * j_]; \
                float4 w1v_ = *(const float4*)&Wl[((TRM) * FHP + 2 * p_ + 1) * FOUT + o0 + 4 * j_]; \
                _Pragma("unroll") for (int i_ = 0; i_ < 4; ++i_) {             \
                    acc[i_][4 * j_ + 0] += k0v_[i_] * w0v_.x + k1v_[i_] * w1v_.x; \
                    acc[i_][4 * j_ + 1] += k0v_[i_] * w0v_.y + k1v_[i_] * w1v_.y; \
                    acc[i_][4 * j_ + 2] += k0v_[i_] * w0v_.z + k1v_[i_] * w1v_.z; \
                    acc[i_][4 * j_ + 3] += k0v_[i_] * w0v_.w + k1v_[i_] * w1v_.w; \
                }                                                              \
            }                                                                  \
        }                                                                      \
    }

    for (int ph = 0; ph < NPH; ++ph) {
        // ---- transformed weight panels (pad rows zeroed)
        for (int idx = t; idx < FHP * FOUT; idx += NT) {
            int f = idx / FOUT, o = idx - f * FOUT;
            float w0 = 0.f, w1 = 0.f, w2 = 0.f;
            if (f < FH) {
                int fg = ph * FH + f;
                w0 = W[o * (3 * FIN) + fg * 3 + 0];
                w1 = W[o * (3 * FIN) + fg * 3 + 1];
                w2 = W[o * (3 * FIN) + fg * 3 + 2];
            }
            Wl[(0 * FHP + f) * FOUT + o] = w0 - w2;
            Wl[(1 * FHP + f) * FOUT + o] = w1;
            Wl[(2 * FHP + f) * FOUT + o] = 2.f * w2;
        }
        // ---- stage x0 slice
        if constexpr (FH == 3) {
            xr[0] = xin[((size_t)b * V + vloc) * 3 + 0];
            xr[1] = xin[((size_t)b * V + vloc) * 3 + 1];
            xr[2] = xin[((size_t)b * V + vloc) * 3 + 2];
            xr[3] = 0.f;
        } else {
#pragma unroll
            for (int gg = 0; gg < GCNT; ++gg) {
                int g = os * GCNT + gg;
                float4 q = *(const float4*)(xin + ((size_t)b * V + vloc) * FIN + ph * FH + 4 * g);
                xr[4 * gg + 0] = q.x; xr[4 * gg + 1] = q.y;
                xr[4 * gg + 2] = q.z; xr[4 * gg + 3] = q.w;
            }
        }
        STAGE_WRITE(xr)
        __syncthreads();
        // ---- gather1 (x1 = L x0) + term0 (x0)
        GATHER(xg)
        TERM(0)
        __syncthreads();
        STAGE_WRITE(xg)          // publish x1 over slab
        __syncthreads();
        // ---- gather2 (x2raw = L x1) + term1 (x1)
        GATHER(xr)
        TERM(1)
        __syncthreads();
        STAGE_WRITE(xr)          // publish x2 over slab
        __syncthreads();
        TERM(2)
        __syncthreads();         // protect slab + Wl for next phase
    }
#undef STAGE_WRITE
#undef GATHER
#undef TERM

    // ---- epilogue
    if constexpr (POOL == 0) {
#pragma unroll
        for (int i = 0; i < 4; ++i) {
            float* orow = out + ((size_t)b * V + 4 * vt + i) * FOUT + o0;
#pragma unroll
            for (int j = 0; j < OW / 4; ++j) {
                float4 st;
                st.x = acc[i][4 * j + 0] + bias[o0 + 4 * j + 0];
                st.y = acc[i][4 * j + 1] + bias[o0 + 4 * j + 1];
                st.z = acc[i][4 * j + 2] + bias[o0 + 4 * j + 2];
                st.w = acc[i][4 * j + 3] + bias[o0 + 4 * j + 3];
                ((float4*)orow)[j] = st;
            }
        }
    } else {
        float* orow = out + ((size_t)b * (V / 4) + vt) * FOUT + o0;
#pragma unroll
        for (int j = 0; j < OW / 4; ++j) {
            float4 st;
#pragma unroll
            for (int q = 0; q < 4; ++q) {
                int o = 4 * j + q;
                float m = fmaxf(fmaxf(acc[0][o], acc[1][o]), fmaxf(acc[2][o], acc[3][o]));
                ((float*)&st)[q] = m + bias[o0 + o];
            }
            ((float4*)orow)[j] = st;
        }
    }
}

// ---------------- FC1: C[512,512] = A[512,4096] * W[512,4096]^T, split-K=16 ----------------
__global__ __launch_bounds__(256) void k_fc1(const float* __restrict__ A,
                                             const float* __restrict__ W,
                                             float* __restrict__ part) {
    __shared__ float As[16][128];
    __shared__ float Bs[16][128];
    const int tid = threadIdx.x;
    const int bm = blockIdx.x, bn = blockIdx.y, bz = blockIdx.z;
    const int m0 = (tid >> 4) << 3;
    const int n0 = (tid & 15) << 3;
    float acc[8][8];
#pragma unroll
    for (int i = 0; i < 8; ++i)
#pragma unroll
        for (int j = 0; j < 8; ++j) acc[i][j] = 0.f;
    const int r = tid >> 1;
    const int c8 = (tid & 1) << 3;
    const float* Ar = A + (size_t)(bm * 128 + r) * 4096 + bz * 256 + c8;
    const float* Wr = W + (size_t)(bn * 128 + r) * 4096 + bz * 256 + c8;
    for (int kt = 0; kt < 256; kt += 16) {
        float4 a0 = *(const float4*)(Ar + kt);
        float4 a1 = *(const float4*)(Ar + kt + 4);
        float4 w0 = *(const float4*)(Wr + kt);
        float4 w1 = *(const float4*)(Wr + kt + 4);
        __syncthreads();
        As[c8 + 0][r] = a0.x; As[c8 + 1][r] = a0.y; As[c8 + 2][r] = a0.z; As[c8 + 3][r] = a0.w;
        As[c8 + 4][r] = a1.x; As[c8 + 5][r] = a1.y; As[c8 + 6][r] = a1.z; As[c8 + 7][r] = a1.w;
        Bs[c8 + 0][r] = w0.x; Bs[c8 + 1][r] = w0.y; Bs[c8 + 2][r] = w0.z; Bs[c8 + 3][r] = w0.w;
        Bs[c8 + 4][r] = w1.x; Bs[c8 + 5][r] = w1.y; Bs[c8 + 6][r] = w1.z; Bs[c8 + 7][r] = w1.w;
        __syncthreads();
#pragma unroll
        for (int k = 0; k < 16; ++k) {
            float am[8], bn_[8];
            *(float4*)&am[0] = *(const float4*)&As[k][m0];
            *(float4*)&am[4] = *(const float4*)&As[k][m0 + 4];
            *(float4*)&bn_[0] = *(const float4*)&Bs[k][n0];
            *(float4*)&bn_[4] = *(const float4*)&Bs[k][n0 + 4];
#pragma unroll
            for (int i = 0; i < 8; ++i)
#pragma unroll
                for (int j = 0; j < 8; ++j) acc[i][j] += am[i] * bn_[j];
        }
    }
    float* P = part + ((size_t)bz * 512 + bm * 128 + m0) * 512 + bn * 128 + n0;
#pragma unroll
    for (int i = 0; i < 8; ++i) {
        float4 s0 = {acc[i][0], acc[i][1], acc[i][2], acc[i][3]};
        float4 s1 = {acc[i][4], acc[i][5], acc[i][6], acc[i][7]};
        *(float4*)(P + i * 512) = s0;
        *(float4*)(P + i * 512 + 4) = s1;
    }
}

__global__ void k_fc1red(const float* __restrict__ part, const float* __restrict__ bias,
                         float* __restrict__ out) {
    int t = blockIdx.x * 256 + threadIdx.x;  // 512*512
    float s = bias[t & 511];
#pragma unroll
    for (int z = 0; z < 16; ++z) s += part[(size_t)z * 262144 + t];
    out[t] = s;
}

// ---------------- FC2: out[512,63] ----------------
__global__ void k_fc2(const float* __restrict__ X, const float* __restrict__ W,
                      const float* __restrict__ bias, float* __restrict__ out) {
    int b = blockIdx.x, c = threadIdx.x;
    if (c >= 63) return;
    const float4* xr = (const float4*)(X + b * 512);
    const float4* wr = (const float4*)(W + c * 512);
    float s = 0.f;
    for (int k = 0; k < 128; ++k) {
        float4 xv = xr[k], wv = wr[k];
        s += xv.x * wv.x + xv.y * wv.y + xv.z * wv.z + xv.w * wv.w;
    }
    out[b * 63 + c] = s + bias[c];
}

extern "C" void kernel_launch(void* const* d_in, const int* in_sizes, int n_in,
                              void* d_out, int out_size, void* d_ws, size_t ws_size,
                              hipStream_t stream) {
    const float* x = (const float*)d_in[0];
    const int* rows0 = (const int*)d_in[1];
    const int* cols0 = (const int*)d_in[2];
    const float* vals0 = (const float*)d_in[3];
    const int* rows1 = (const int*)d_in[4];
    const int* cols1 = (const int*)d_in[5];
    const float* vals1 = (const float*)d_in[6];
    const float* W0 = (const float*)d_in[7];  const float* b0 = (const float*)d_in[8];
    const float* W1 = (const float*)d_in[9];  const float* b1 = (const float*)d_in[10];
    const float* W2 = (const float*)d_in[11]; const float* b2 = (const float*)d_in[12];
    const float* W3 = (const float*)d_in[13]; const float* b3 = (const float*)d_in[14];
    const float* fcW1 = (const float*)d_in[15]; const float* fcb1 = (const float*)d_in[16];
    const float* fcW2 = (const float*)d_in[17]; const float* fcb2 = (const float*)d_in[18];
    float* out = (float*)d_out;

    float* wsf = (float*)d_ws;
    // small region
    int* off0 = (int*)(wsf + 0);          // 1025
    int* off1 = (int*)(wsf + 1088);       // 257
    int* deg0 = (int*)(wsf + 1408);       // 1024
    int* deg1 = (int*)(wsf + 2432);       // 256
    int2* epk0 = (int2*)(wsf + 4096);     // 8192 int2 -> [4096, 20480)
    int2* epk1 = (int2*)(wsf + 20480);    // 2048 int2 -> [20480, 24576)

    float* A1  = wsf + 65536;             // 16,777,216  [B,1024,32]
    float* P1  = A1 + 16777216;           //  4,194,304  [B,256,32]
    float* A3  = P1 + 4194304;            //  8,388,608  [B,256,64]
    float* FCB = A3 + 8388608;            //  2,097,152  [B,4096]
    float* PART = FCB + 2097152;          //  4,194,304  [16,512,512]
    float* FC1O = PART + 4194304;         //    262,144  [512,512]
    (void)in_sizes; (void)n_in; (void)out_size; (void)ws_size;

    hipMemsetAsync(wsf + 1408, 0, 1280 * 4, stream);
    k_deg<<<E0 / 256, 256, 0, stream>>>(rows0, E0, deg0);
    k_deg<<<E1 / 256, 256, 0, stream>>>(rows1, E1, deg1);
    k_scan<<<1, 1024, 0, stream>>>(deg0, off0, V0);
    k_scan<<<1, 1024, 0, stream>>>(deg1, off1, V1);
    k_fillp<<<E0 / 256, 256, 0, stream>>>(rows0, cols0, vals0, E0, off0, epk0);
    k_fillp<<<E1 / 256, 256, 0, stream>>>(rows1, cols1, vals1, E1, off1, epk1);

    // conv1: 3->32, 1024 thr, LDS ~18 KB
    k_conv<V0, 3, 3, 32, 1, 0><<<BB, 1024, 0, stream>>>(x, W0, b0, A1, off0, epk0);
    // conv2+pool: 32->32, FH=8, 1024 thr, LDS ~36 KB, 2 blk/CU
    k_conv<V0, 32, 8, 32, 1, 1><<<BB, 1024, 0, stream>>>(A1, W1, b1, P1, off0, epk0);
    // conv3: 32->64, OS=2, 512 thr, LDS ~14.5 KB, 2 blk/CU
    k_conv<V1, 32, 8, 64, 2, 0><<<BB, 512, 0, stream>>>(P1, W2, b2, A3, off1, epk1);
    // conv4+pool: 64->64, OS=2, 512 thr, LDS ~14.5 KB, 2 blk/CU
    k_conv<V1, 64, 8, 64, 2, 1><<<BB, 512, 0, stream>>>(A3, W3, b3, FCB, off1, epk1);

    // head (FCB is [B, 4096] in reference order)
    k_fc1<<<dim3(4, 4, 16), 256, 0, stream>>>(FCB, fcW1, PART);
    k_fc1red<<<1024, 256, 0, stream>>>(PART, fcb1, FC1O);
    k_fc2<<<BB, 64, 0, stream>>>(FC1O, fcW2, fcb2, out);
}

// Round 9
// 603.744 us; speedup vs baseline: 8.1770x; 2.2982x over previous
//
#include <hip/hip_runtime.h>

#define BB 512
#define V0 1024
#define V1 256
#define E0 8192
#define E1 2048

// ---------------- CSR build (deterministic) ----------------
__global__ void k_deg(const int* __restrict__ rows, int E, int* __restrict__ deg) {
    int t = blockIdx.x * 256 + threadIdx.x;
    if (t < E) atomicAdd(&deg[rows[t]], 1);
}

__global__ void k_scan(const int* __restrict__ deg, int* __restrict__ off, int V) {
    __shared__ int s[1024];
    int t = threadIdx.x;
    s[t] = (t < V) ? deg[t] : 0;
    __syncthreads();
    for (int d = 1; d < 1024; d <<= 1) {
        int val = (t >= d) ? s[t - d] : 0;
        __syncthreads();
        s[t] += val;
        __syncthreads();
    }
    if (t < V) off[t + 1] = s[t];
    if (t == 0) off[0] = 0;
}

// stable fill: edge e goes to off[row] + (#earlier edges with same row)
__global__ void k_fill(const int* __restrict__ rows, const int* __restrict__ cols,
                       const float* __restrict__ vals, int E,
                       const int* __restrict__ off, int* __restrict__ scol,
                       float* __restrict__ sval) {
    __shared__ int rs[256];
    int e = blockIdx.x * 256 + threadIdx.x;
    int r = (e < E) ? rows[e] : -1;
    int rank = 0;
    for (int c0 = 0; c0 <= (int)blockIdx.x; ++c0) {
        __syncthreads();
        int idx = c0 * 256 + threadIdx.x;
        rs[threadIdx.x] = (idx < E) ? rows[idx] : -2;
        __syncthreads();
        int lim = e - c0 * 256;
        if (lim > 256) lim = 256;
        for (int j = 0; j < lim; ++j) rank += (rs[j] == r) ? 1 : 0;
    }
    if (e < E) {
        int p = off[r] + rank;
        scol[p] = cols[e];
        sval[p] = vals[e];
    }
}

// ---------------- fused cheby conv, batch-major, feature-major LDS (padded) ----------------
// xin [B, V, FIN] (row-major), out [B, V or V/4, FOUT].
// Block = NB*V threads covering NB batch-slices of V vertices.
// Per phase (FH input features): stage x0 slice feature-major with PADDED column
// stride NCP = NC+4. x1 = L x0 -> LDS, x2raw = L x1 -> LDS, then register-tiled GEMM
// acc += [x0|x1|x2raw]^T (K=3*FH) * Wl (transformed panels: W0-W2 | W1 | 2*W2).
// POOL: 0 = none, 1 = max over the thread's 4-vertex microtile (stride-4 pool).
template <int V, int NB, int FIN, int FH, int FOUT, int POOL>
__global__ __launch_bounds__(NB * V) void k_conv(
    const float* __restrict__ xin, const float* __restrict__ W,
    const float* __restrict__ bias, float* __restrict__ out,
    const int* __restrict__ off, const int* __restrict__ scol,
    const float* __restrict__ sval) {
    constexpr int NPH = FIN / FH;
    constexpr int OW = FOUT / 4;   // outputs per thread
    constexpr int NC = NB * V;     // LDS columns (== blockDim.x)
    constexpr int NCP = NC + 4;    // padded column stride (16B aligned)
    __shared__ float xsA[3 * FH * NCP];
    __shared__ float Wl[3 * FH * FOUT];

    const int t = threadIdx.x;
    const int bb = (NB == 1) ? 0 : (t / V);
    const int vloc = (NB == 1) ? t : (t - bb * V);
    const int b = blockIdx.x * NB + bb;
    const int vt = vloc >> 2;
    const int ot = vloc & 3;
    const int o0 = ot * OW;
    const int colg = bb * V;

    const int s0 = off[vloc];
    const int e0 = off[vloc + 1];

    float acc[4][OW];
#pragma unroll
    for (int i = 0; i < 4; ++i)
#pragma unroll
        for (int o = 0; o < OW; ++o) acc[i][o] = 0.f;

    for (int ph = 0; ph < NPH; ++ph) {
        // ---- transformed weight panels for this feature slice (k-major [k][o])
        for (int idx = t; idx < FH * FOUT; idx += NC) {
            int f = idx / FOUT, o = idx - f * FOUT;
            int fg = ph * FH + f;
            float w0 = W[o * (3 * FIN) + fg * 3 + 0];
            float w1 = W[o * (3 * FIN) + fg * 3 + 1];
            float w2 = W[o * (3 * FIN) + fg * 3 + 2];
            Wl[f * FOUT + o] = w0 - w2;
            Wl[(FH + f) * FOUT + o] = w1;
            Wl[(2 * FH + f) * FOUT + o] = 2.f * w2;
        }
        // ---- stage x0 feature slice, feature-major (padded stride)
        if constexpr (FH == 3) {
#pragma unroll
            for (int f = 0; f < 3; ++f)
                xsA[f * NCP + colg + vloc] = xin[((size_t)b * V + vloc) * 3 + f];
        } else {
#pragma unroll
            for (int j = 0; j < FH / 4; ++j) {
                float4 q = *(const float4*)(xin + ((size_t)b * V + vloc) * FIN + ph * FH + 4 * j);
                xsA[(4 * j + 0) * NCP + colg + vloc] = q.x;
                xsA[(4 * j + 1) * NCP + colg + vloc] = q.y;
                xsA[(4 * j + 2) * NCP + colg + vloc] = q.z;
                xsA[(4 * j + 3) * NCP + colg + vloc] = q.w;
            }
        }
        __syncthreads();
        // ---- x1 = L x0
        {
            float r[FH];
#pragma unroll
            for (int f = 0; f < FH; ++f) r[f] = 0.f;
            for (int p = s0; p < e0; ++p) {
                int c = colg + scol[p];
                float w = sval[p];
#pragma unroll
                for (int f = 0; f < FH; ++f) r[f] += w * xsA[f * NCP + c];
            }
#pragma unroll
            for (int f = 0; f < FH; ++f) xsA[(FH + f) * NCP + colg + vloc] = r[f];
        }
        __syncthreads();
        // ---- x2raw = L x1
        {
            float r[FH];
#pragma unroll
            for (int f = 0; f < FH; ++f) r[f] = 0.f;
            for (int p = s0; p < e0; ++p) {
                int c = colg + scol[p];
                float w = sval[p];
#pragma unroll
                for (int f = 0; f < FH; ++f) r[f] += w * xsA[(FH + f) * NCP + c];
            }
#pragma unroll
            for (int f = 0; f < FH; ++f) xsA[(2 * FH + f) * NCP + colg + vloc] = r[f];
        }
        __syncthreads();
        // ---- GEMM accumulate: K = 3*FH
        {
            const int a0 = colg + 4 * vt;
#pragma unroll 4
            for (int k = 0; k < 3 * FH; ++k) {
                float4 a = *(const float4*)&xsA[k * NCP + a0];
                float av[4] = {a.x, a.y, a.z, a.w};
#pragma unroll
                for (int j = 0; j < OW / 4; ++j) {
                    float4 wv = *(const float4*)&Wl[k * FOUT + o0 + 4 * j];
#pragma unroll
                    for (int i = 0; i < 4; ++i) {
                        acc[i][4 * j + 0] += av[i] * wv.x;
                        acc[i][4 * j + 1] += av[i] * wv.y;
                        acc[i][4 * j + 2] += av[i] * wv.z;
                        acc[i][4 * j + 3] += av[i] * wv.w;
                    }
                }
            }
        }
        __syncthreads();  // protect LDS before next phase overwrites
    }

    // ---- epilogue
    if constexpr (POOL == 0) {
#pragma unroll
        for (int i = 0; i < 4; ++i) {
            float* orow = out + ((size_t)b * V + 4 * vt + i) * FOUT + o0;
#pragma unroll
            for (int j = 0; j < OW / 4; ++j) {
                float4 st;
                st.x = acc[i][4 * j + 0] + bias[o0 + 4 * j + 0];
                st.y = acc[i][4 * j + 1] + bias[o0 + 4 * j + 1];
                st.z = acc[i][4 * j + 2] + bias[o0 + 4 * j + 2];
                st.w = acc[i][4 * j + 3] + bias[o0 + 4 * j + 3];
                ((float4*)orow)[j] = st;
            }
        }
    } else {
        float* orow = out + ((size_t)b * (V / 4) + vt) * FOUT + o0;
#pragma unroll
        for (int j = 0; j < OW / 4; ++j) {
            float4 st;
#pragma unroll
            for (int q = 0; q < 4; ++q) {
                int o = 4 * j + q;
                float m = fmaxf(fmaxf(acc[0][o], acc[1][o]), fmaxf(acc[2][o], acc[3][o]));
                ((float*)&st)[q] = m + bias[o0 + o];
            }
            ((float4*)orow)[j] = st;
        }
    }
}

// ---------------- FC1: C[512,512] = A[512,4096] * W[512,4096]^T, split-K=16 ----------------
__global__ __launch_bounds__(256) void k_fc1(const float* __restrict__ A,
                                             const float* __restrict__ W,
                                             float* __restrict__ part) {
    __shared__ float As[16][128];
    __shared__ float Bs[16][128];
    const int tid = threadIdx.x;
    const int bm = blockIdx.x, bn = blockIdx.y, bz = blockIdx.z;
    const int m0 = (tid >> 4) << 3;
    const int n0 = (tid & 15) << 3;
    float acc[8][8];
#pragma unroll
    for (int i = 0; i < 8; ++i)
#pragma unroll
        for (int j = 0; j < 8; ++j) acc[i][j] = 0.f;
    const int r = tid >> 1;
    const int c8 = (tid & 1) << 3;
    const float* Ar = A + (size_t)(bm * 128 + r) * 4096 + bz * 256 + c8;
    const float* Wr = W + (size_t)(bn * 128 + r) * 4096 + bz * 256 + c8;
    for (int kt = 0; kt < 256; kt += 16) {
        float4 a0 = *(const float4*)(Ar + kt);
        float4 a1 = *(const float4*)(Ar + kt + 4);
        float4 w0 = *(const float4*)(Wr + kt);
        float4 w1 = *(const float4*)(Wr + kt + 4);
        __syncthreads();
        As[c8 + 0][r] = a0.x; As[c8 + 1][r] = a0.y; As[c8 + 2][r] = a0.z; As[c8 + 3][r] = a0.w;
        As[c8 + 4][r] = a1.x; As[c8 + 5][r] = a1.y; As[c8 + 6][r] = a1.z; As[c8 + 7][r] = a1.w;
        Bs[c8 + 0][r] = w0.x; Bs[c8 + 1][r] = w0.y; Bs[c8 + 2][r] = w0.z; Bs[c8 + 3][r] = w0.w;
        Bs[c8 + 4][r] = w1.x; Bs[c8 + 5][r] = w1.y; Bs[c8 + 6][r] = w1.z; Bs[c8 + 7][r] = w1.w;
        __syncthreads();
#pragma unroll
        for (int k = 0; k < 16; ++k) {
            float am[8], bn_[8];
            *(float4*)&am[0] = *(const float4*)&As[k][m0];
            *(float4*)&am[4] = *(const float4*)&As[k][m0 + 4];
            *(float4*)&bn_[0] = *(const float4*)&Bs[k][n0];
            *(float4*)&bn_[4] = *(const float4*)&Bs[k][n0 + 4];
#pragma unroll
            for (int i = 0; i < 8; ++i)
#pragma unroll
                for (int j = 0; j < 8; ++j) acc[i][j] += am[i] * bn_[j];
        }
    }
    float* P = part + ((size_t)bz * 512 + bm * 128 + m0) * 512 + bn * 128 + n0;
#pragma unroll
    for (int i = 0; i < 8; ++i) {
        float4 s0 = {acc[i][0], acc[i][1], acc[i][2], acc[i][3]};
        float4 s1 = {acc[i][4], acc[i][5], acc[i][6], acc[i][7]};
        *(float4*)(P + i * 512) = s0;
        *(float4*)(P + i * 512 + 4) = s1;
    }
}

__global__ void k_fc1red(const float* __restrict__ part, const float* __restrict__ bias,
                         float* __restrict__ out) {
    int t = blockIdx.x * 256 + threadIdx.x;  // 512*512
    float s = bias[t & 511];
#pragma unroll
    for (int z = 0; z < 16; ++z) s += part[(size_t)z * 262144 + t];
    out[t] = s;
}

// ---------------- FC2: out[512,63] ----------------
__global__ void k_fc2(const float* __restrict__ X, const float* __restrict__ W,
                      const float* __restrict__ bias, float* __restrict__ out) {
    int b = blockIdx.x, c = threadIdx.x;
    if (c >= 63) return;
    const float4* xr = (const float4*)(X + b * 512);
    const float4* wr = (const float4*)(W + c * 512);
    float s = 0.f;
    for (int k = 0; k < 128; ++k) {
        float4 xv = xr[k], wv = wr[k];
        s += xv.x * wv.x + xv.y * wv.y + xv.z * wv.z + xv.w * wv.w;
    }
    out[b * 63 + c] = s + bias[c];
}

extern "C" void kernel_launch(void* const* d_in, const int* in_sizes, int n_in,
                              void* d_out, int out_size, void* d_ws, size_t ws_size,
                              hipStream_t stream) {
    const float* x = (const float*)d_in[0];
    const int* rows0 = (const int*)d_in[1];
    const int* cols0 = (const int*)d_in[2];
    const float* vals0 = (const float*)d_in[3];
    const int* rows1 = (const int*)d_in[4];
    const int* cols1 = (const int*)d_in[5];
    const float* vals1 = (const float*)d_in[6];
    const float* W0 = (const float*)d_in[7];  const float* b0 = (const float*)d_in[8];
    const float* W1 = (const float*)d_in[9];  const float* b1 = (const float*)d_in[10];
    const float* W2 = (const float*)d_in[11]; const float* b2 = (const float*)d_in[12];
    const float* W3 = (const float*)d_in[13]; const float* b3 = (const float*)d_in[14];
    const float* fcW1 = (const float*)d_in[15]; const float* fcb1 = (const float*)d_in[16];
    const float* fcW2 = (const float*)d_in[17]; const float* fcb2 = (const float*)d_in[18];
    float* out = (float*)d_out;

    float* wsf = (float*)d_ws;
    // CSR region (aliased ints/floats), 65536 floats
    int* off0 = (int*)(wsf + 0);          // 1025
    int* scol0 = (int*)(wsf + 2048);      // 8192
    float* sval0 = wsf + 10240;           // 8192
    int* off1 = (int*)(wsf + 18432);      // 257
    int* scol1 = (int*)(wsf + 20480);     // 2048
    float* sval1 = wsf + 22528;           // 2048
    int* deg0 = (int*)(wsf + 24576);      // 1024
    int* deg1 = (int*)(wsf + 25600);      // 256

    float* A1  = wsf + 65536;             // 16,777,216  [B,1024,32]
    float* P1  = A1 + 16777216;           //  4,194,304  [B,256,32]
    float* A3  = P1 + 4194304;            //  8,388,608  [B,256,64]
    float* FCB = A3 + 8388608;            //  2,097,152  [B,4096]
    float* PART = FCB + 2097152;          //  4,194,304  [16,512,512]
    float* FC1O = PART + 4194304;         //    262,144  [512,512]
    (void)in_sizes; (void)n_in; (void)out_size; (void)ws_size;

    hipMemsetAsync(wsf, 0, 65536 * 4, stream);
    k_deg<<<E0 / 256, 256, 0, stream>>>(rows0, E0, deg0);
    k_deg<<<E1 / 256, 256, 0, stream>>>(rows1, E1, deg1);
    k_scan<<<1, 1024, 0, stream>>>(deg0, off0, V0);
    k_scan<<<1, 1024, 0, stream>>>(deg1, off1, V1);
    k_fill<<<E0 / 256, 256, 0, stream>>>(rows0, cols0, vals0, E0, off0, scol0, sval0);
    k_fill<<<E1 / 256, 256, 0, stream>>>(rows1, cols1, vals1, E1, off1, scol1, sval1);

    // conv1: level0, 3->32             1024 thr, LDS ~38 KB
    k_conv<V0, 1, 3, 3, 32, 0><<<BB, 1024, 0, stream>>>(x, W0, b0, A1, off0, scol0, sval0);
    // conv2+pool: level0, 32->32, FH=4 -> LDS ~51 KB -> 2 blocks/CU
    k_conv<V0, 1, 32, 4, 32, 1><<<BB, 1024, 0, stream>>>(A1, W1, b1, P1, off0, scol0, sval0);
    // conv3: level1, 32->64            256 thr, 512 blocks, LDS ~31 KB
    k_conv<V1, 1, 32, 8, 64, 0><<<BB, 256, 0, stream>>>(P1, W2, b2, A3, off1, scol1, sval1);
    // conv4+pool: level1, 64->64       256 thr, 512 blocks, LDS ~31 KB
    k_conv<V1, 1, 64, 8, 64, 1><<<BB, 256, 0, stream>>>(A3, W3, b3, FCB, off1, scol1, sval1);

    // head (FCB is [B, 4096] in reference order)
    k_fc1<<<dim3(4, 4, 16), 256, 0, stream>>>(FCB, fcW1, PART);
    k_fc1red<<<1024, 256, 0, stream>>>(PART, fcb1, FC1O);
    k_fc2<<<BB, 64, 0, stream>>>(FC1O, fcW2, fcb2, out);
}